// Round 1
// baseline (232.601 us; speedup 1.0000x reference)
//
#include <hip/hip_runtime.h>
#include <math.h>

// YOLO loss: pred/target (BATCH,7,7,30) f32, choice (BATCH,7,7) i32
// -> 4 scalars: (loc_loss, cls_loss, obj_loss, noobj_loss)
// Memory-bound streaming reduction (~196 MB read). One thread per cell.

constexpr int NCH = 30;   // 5*B + C
constexpr int CC  = 20;   // classes
constexpr int PAD = 16;   // floats per accumulator slot (64 B -> separate lines)

__global__ __launch_bounds__(256) void yolo_main(
    const float* __restrict__ pred, const float* __restrict__ target,
    const int* __restrict__ choice, float* __restrict__ acc, int ncells)
{
    int cell = blockIdx.x * 256 + threadIdx.x;

    float s_loc = 0.f, s_ce = 0.f, s_obj = 0.f, s_no = 0.f;
    float n_obj = 0.f, n_no = 0.f;

    if (cell < ncells) {
        // cell base byte offset = cell*120, always 8B aligned -> float2 loads
        const float2* P2 = (const float2*)(pred + (size_t)cell * NCH);
        const float2* T2 = (const float2*)(target + (size_t)cell * NCH);
        float p[NCH], t[NCH];
        #pragma unroll
        for (int i = 0; i < NCH / 2; ++i) {
            float2 v = P2[i]; p[2 * i] = v.x; p[2 * i + 1] = v.y;
        }
        #pragma unroll
        for (int i = 0; i < NCH / 2; ++i) {
            float2 w = T2[i]; t[2 * i] = w.x; t[2 * i + 1] = w.y;
        }
        bool c = choice[cell] != 0;

        float tconf = t[4];
        bool  obj = tconf > 0.0f;
        float m = obj ? 1.0f : 0.0f;

        // constant-index selects (keep arrays in registers)
        float pxy0 = c ? p[0] : p[5];
        float pxy1 = c ? p[1] : p[6];
        float pwh0 = c ? p[2] : p[7];
        float pwh1 = c ? p[3] : p[8];
        float pobj = c ? p[4] : p[9];
        float txy0 = c ? t[0] : t[5];
        float txy1 = c ? t[1] : t[6];
        float twh0 = c ? t[2] : t[7];
        float twh1 = c ? t[3] : t[8];
        if (!obj) { twh0 = 1.0f; twh1 = 1.0f; }
        float tobj = c ? tconf : t[9];

        float dx = pxy0 - txy0, dy = pxy1 - txy1;
        float dw = pwh0 - sqrtf(twh0), dh = pwh1 - sqrtf(twh1);
        float loc_cell = 0.5f * (dx * dx + dy * dy) + 0.5f * (dw * dw + dh * dh);
        s_loc = m * loc_cell;

        float dob = pobj - tobj;
        s_obj = m * dob * dob;

        float nm = (tconf == 0.0f) ? 1.0f : 0.0f;
        float d4 = p[4] - tconf, d9 = p[9] - t[9];
        s_no = nm * (d4 * d4 + d9 * d9);   // both noobj terms share divisor n_no

        n_obj = m;
        n_no  = nm;

        // argmax over target classes (first max wins: strict >)
        int   tcls  = 0;
        float tbest = t[10];
        #pragma unroll
        for (int i = 1; i < CC; ++i) {
            float v = t[10 + i];
            if (v > tbest) { tbest = v; tcls = i; }
        }
        // sm = softmax(logits); ce = log(sum_j exp(sm_j)) - sm[tcls]
        float mx = p[10];
        #pragma unroll
        for (int i = 1; i < CC; ++i) mx = fmaxf(mx, p[10 + i]);
        float e[CC];
        float Z = 0.f;
        #pragma unroll
        for (int i = 0; i < CC; ++i) { e[i] = __expf(p[10 + i] - mx); Z += e[i]; }
        float rZ = 1.0f / Z;
        float Z2 = 0.f, sm_t = 0.f;
        #pragma unroll
        for (int i = 0; i < CC; ++i) {
            float sm = e[i] * rZ;          // in (0,1] -> exp safe without max-sub
            Z2 += __expf(sm);
            if (i == tcls) sm_t = sm;
        }
        float ce = __logf(Z2) - sm_t;
        s_ce = m * ce;
    }

    // wave(64)-level shuffle reduction of the 6 partials
    #pragma unroll
    for (int off = 32; off > 0; off >>= 1) {
        s_loc += __shfl_down(s_loc, off);
        s_ce  += __shfl_down(s_ce,  off);
        s_obj += __shfl_down(s_obj, off);
        s_no  += __shfl_down(s_no,  off);
        n_obj += __shfl_down(n_obj, off);
        n_no  += __shfl_down(n_no,  off);
    }

    __shared__ float red[4][6];
    int wave = threadIdx.x >> 6;
    int lane = threadIdx.x & 63;
    if (lane == 0) {
        red[wave][0] = s_loc; red[wave][1] = s_ce;  red[wave][2] = s_obj;
        red[wave][3] = s_no;  red[wave][4] = n_obj; red[wave][5] = n_no;
    }
    __syncthreads();
    if (threadIdx.x < 6) {
        float v = red[0][threadIdx.x] + red[1][threadIdx.x] +
                  red[2][threadIdx.x] + red[3][threadIdx.x];
        atomicAdd(&acc[threadIdx.x * PAD], v);  // padded: each counter on own 64B line
    }
}

__global__ void yolo_final(const float* __restrict__ acc, float* __restrict__ out) {
    float S_loc = acc[0 * PAD], S_ce = acc[1 * PAD], S_obj = acc[2 * PAD];
    float S_no  = acc[3 * PAD], N_ob = acc[4 * PAD], N_no = acc[5 * PAD];
    out[0] = 5.0f * S_loc;                    // loc_loss  (L_COORD = 5)
    out[1] = S_ce / fmaxf(N_ob, 1.0f);        // cls_loss
    out[2] = S_obj;                           // obj_loss
    out[3] = 0.5f * S_no / fmaxf(N_no, 1.0f); // noobj_loss (L_NOOBJ = 0.5)
}

extern "C" void kernel_launch(void* const* d_in, const int* in_sizes, int n_in,
                              void* d_out, int out_size, void* d_ws, size_t ws_size,
                              hipStream_t stream) {
    const float* pred   = (const float*)d_in[0];
    const float* target = (const float*)d_in[1];
    const int*   choice = (const int*)d_in[2];
    float* out = (float*)d_out;
    float* acc = (float*)d_ws;

    int ncells = in_sizes[2];                 // BATCH * S * S = 802816
    hipMemsetAsync(d_ws, 0, 6 * PAD * sizeof(float), stream);
    int blocks = (ncells + 255) / 256;        // 3136 exactly
    yolo_main<<<blocks, 256, 0, stream>>>(pred, target, choice, acc, ncells);
    yolo_final<<<1, 1, 0, stream>>>(acc, out);
}